// Round 1
// baseline (1463.947 us; speedup 1.0000x reference)
//
#include <hip/hip_runtime.h>
#include <math.h>

// SchNet forward, MI355X. Round 12 = 128x128 MFMA tiles w/ 64x64 wave tiles.
// r11 analysis: 64x64 tiles were LDS-bound (per block-chunk: 48KB LDS traffic
// = 384 clk vs 192 clk MFMA; flops/LDS-byte = 24) and the b64 staging writes
// hit only even 8B slots (2x serialization -> 7.6M SQ_LDS_BANK_CONFLICT).
// Changes:
//  - TM=TN=128, 4 waves, each wave owns 64x64 (4x4 quadrants of 16x16x32):
//    flops/LDS-byte doubles to 48; block-chunks drop 4x (29.8K -> 7.5K
//    barrier pairs per dispatch); A-unpack VALU amortized 2x.
//  - all LDS staging via b128 writes: slot pattern (5*row + sub) % 8 is
//    exactly 8 lanes/slot = conflict-free (b64 writes were 2x imbalanced).
//  - __launch_bounds__(256,2): ~190 VGPR (64 acc + 64 frags + 32 prefetch),
//    2 blocks/CU, LDS 40KB single-buffered + register prefetch (m97 style).
//  - gemm_k (final 128x600x600, was 63us at 20 blocks / VALU 1.1% = pure
//    latency) -> pool_mm_k: 256 blocks, 1 col/thread, A-row in LDS.
// Numerics bit-identical to r11 (same K order, same tri-MFMA hi/lo split).
// Stack: segment pool, batched tab GEMMs, packed bf16 hi/lo residual,
// HP=608 sector alignment, XCD swizzle, CSR gather, filter-table + lerp.

#define N_ATOMS 10000
#define E_EDGES 64000
#define B_MOLS  128
#define H_DIM   600
#define HP      608            // padded leading dim (608*4B = 38 sectors)
#define G_DIM   50
#define L_LAYERS 6
#define M_TAB   1024
#define DMAX    8.67f
#define LOG2C   0.69314718056f

#define TM 128
#define TN 128
#define TK 32
#define SA 40          // LDS row stride in shorts (80B rows, 16B-slot balanced)

typedef __attribute__((ext_vector_type(8))) short bf16x8;
typedef __attribute__((ext_vector_type(4))) float f32x4;

__device__ __forceinline__ float sspf(float x) {
    return fmaxf(x, 0.0f) + log1pf(expf(-fabsf(x))) - LOG2C;
}
__device__ __forceinline__ short f2bf(float x) {
    unsigned u = __float_as_uint(x);
    unsigned r = (u + 0x7FFF + ((u >> 16) & 1)) >> 16;   // RNE
    return (short)r;
}
__device__ __forceinline__ float bf2f(short h) {
    return __uint_as_float(((unsigned)(unsigned short)h) << 16);
}
__device__ __forceinline__ int packsplit(float x) {
    short hi = f2bf(x);
    short lo = f2bf(x - bf2f(hi));
    return ((int)hi << 16) | ((int)lo & 0xffff);
}
__device__ __forceinline__ float unpackf(int p) {
    float fh = __uint_as_float((unsigned)p & 0xffff0000u);
    float fl = __uint_as_float(((unsigned)p) << 16);
    return fh + fl;
}

// 16 packed ints -> 8+8 hi shorts and 8+8 lo shorts (two b128 writes each)
__device__ __forceinline__ void unpack8(const int4& p0, const int4& p1,
                                        bf16x8& hi, bf16x8& lo)
{
    hi = (bf16x8){ (short)(p0.x >> 16), (short)(p0.y >> 16),
                   (short)(p0.z >> 16), (short)(p0.w >> 16),
                   (short)(p1.x >> 16), (short)(p1.y >> 16),
                   (short)(p1.z >> 16), (short)(p1.w >> 16) };
    lo = (bf16x8){ (short)p0.x, (short)p0.y, (short)p0.z, (short)p0.w,
                   (short)p1.x, (short)p1.y, (short)p1.z, (short)p1.w };
}

// ---------------------------------------------------------------- MFMA GEMM
// outP = packsplit(op(A @ B + bias [+ unpack(outP)])). A: packed int [Ma][lda]
// (zero-padded cols). B: TRANSPOSED pre-split bf16 hi/lo [Nc][ldb] (zero-
// padded k). K % 32 == 0. Output ld = HP, pad cols 0. 1D grid, XCD swizzle.
// 128x128 tile, 4 waves (2x2), wave tile 64x64. Staging rows clamped; OOB
// contributions masked by the epilogue.
template<bool BIAS, bool ACT, bool ACCUM>
__global__ __launch_bounds__(256, 2)
void gemm_mfma(const int* __restrict__ A, int lda,
               const short* __restrict__ Bh, const short* __restrict__ Bl, int ldb,
               const float* __restrict__ bias,
               int* __restrict__ outP,
               int Ma, int K, int Nc)
{
    const int NT = (Nc + TN - 1) / TN;
    const int f = blockIdx.x;
    const int xcd = f & 7, s = f >> 3;
    const int n0 = (s % NT) * TN;
    const int m0 = (xcd + 8 * (s / NT)) * TM;
    if (m0 >= Ma) return;

    __shared__ __align__(16) short As[2][TM * SA];
    __shared__ __align__(16) short Bs[2][TN * SA];

    const int tid = threadIdx.x;
    const int lane = tid & 63, wid = tid >> 6;
    const int wm = (wid >> 1) * 64, wn = (wid & 1) * 64;
    const int l15 = lane & 15, quad = lane >> 4;

    // staging: thread t handles row t>>1 (0..127), k-half (t&1)*16 elements
    const int srow  = tid >> 1;
    const int shalf = (tid & 1) << 4;   // 0 or 16 (ints for A, shorts for B)

    const int gm = min(m0 + srow, Ma - 1);
    const int gn = min(n0 + srow, Nc - 1);
    const int*   aPtr  = A  + (size_t)gm * lda + shalf;
    const short* bPtrH = Bh + (size_t)gn * ldb + shalf;
    const short* bPtrL = Bl + (size_t)gn * ldb + shalf;

    f32x4 acc[4][4];
    #pragma unroll
    for (int i = 0; i < 4; ++i)
        #pragma unroll
        for (int j = 0; j < 4; ++j)
            acc[i][j] = (f32x4){0.f, 0.f, 0.f, 0.f};

    int4 ra0, ra1, ra2, ra3;
    bf16x8 rbh0, rbh1, rbl0, rbl1;

    // prefetch chunk 0
    ra0 = *(const int4*)aPtr;       ra1 = *(const int4*)(aPtr + 4);
    ra2 = *(const int4*)(aPtr + 8); ra3 = *(const int4*)(aPtr + 12);
    rbh0 = *(const bf16x8*)bPtrH;   rbh1 = *(const bf16x8*)(bPtrH + 8);
    rbl0 = *(const bf16x8*)bPtrL;   rbl1 = *(const bf16x8*)(bPtrL + 8);
    aPtr += TK; bPtrH += TK; bPtrL += TK;

    for (int k0 = 0; k0 < K; k0 += TK) {
        {
            bf16x8 h01, l01, h23, l23;
            unpack8(ra0, ra1, h01, l01);
            unpack8(ra2, ra3, h23, l23);
            *(bf16x8*)&As[0][srow * SA + shalf]     = h01;
            *(bf16x8*)&As[0][srow * SA + shalf + 8] = h23;
            *(bf16x8*)&As[1][srow * SA + shalf]     = l01;
            *(bf16x8*)&As[1][srow * SA + shalf + 8] = l23;
            *(bf16x8*)&Bs[0][srow * SA + shalf]     = rbh0;
            *(bf16x8*)&Bs[0][srow * SA + shalf + 8] = rbh1;
            *(bf16x8*)&Bs[1][srow * SA + shalf]     = rbl0;
            *(bf16x8*)&Bs[1][srow * SA + shalf + 8] = rbl1;
        }
        __syncthreads();

        if (k0 + TK < K) {
            ra0 = *(const int4*)aPtr;       ra1 = *(const int4*)(aPtr + 4);
            ra2 = *(const int4*)(aPtr + 8); ra3 = *(const int4*)(aPtr + 12);
            rbh0 = *(const bf16x8*)bPtrH;   rbh1 = *(const bf16x8*)(bPtrH + 8);
            rbl0 = *(const bf16x8*)bPtrL;   rbl1 = *(const bf16x8*)(bPtrL + 8);
            aPtr += TK; bPtrH += TK; bPtrL += TK;
        }

        bf16x8 a_h[4], a_l[4], b_h[4], b_l[4];
        #pragma unroll
        for (int mi = 0; mi < 4; ++mi) {
            int row = wm + mi * 16 + l15;
            a_h[mi] = *(const bf16x8*)&As[0][row * SA + quad * 8];
            a_l[mi] = *(const bf16x8*)&As[1][row * SA + quad * 8];
        }
        #pragma unroll
        for (int ni = 0; ni < 4; ++ni) {
            int col = wn + ni * 16 + l15;
            b_h[ni] = *(const bf16x8*)&Bs[0][col * SA + quad * 8];
            b_l[ni] = *(const bf16x8*)&Bs[1][col * SA + quad * 8];
        }

        #pragma unroll
        for (int mi = 0; mi < 4; ++mi)
            #pragma unroll
            for (int ni = 0; ni < 4; ++ni) {
                acc[mi][ni] = __builtin_amdgcn_mfma_f32_16x16x32_bf16(
                    a_h[mi], b_h[ni], acc[mi][ni], 0, 0, 0);
                acc[mi][ni] = __builtin_amdgcn_mfma_f32_16x16x32_bf16(
                    a_h[mi], b_l[ni], acc[mi][ni], 0, 0, 0);
                acc[mi][ni] = __builtin_amdgcn_mfma_f32_16x16x32_bf16(
                    a_l[mi], b_h[ni], acc[mi][ni], 0, 0, 0);
            }
        __syncthreads();
    }

    #pragma unroll
    for (int mi = 0; mi < 4; ++mi) {
        #pragma unroll
        for (int r = 0; r < 4; ++r) {
            int row = m0 + wm + mi * 16 + quad * 4 + r;
            if (row >= Ma) continue;
            #pragma unroll
            for (int ni = 0; ni < 4; ++ni) {
                int col = n0 + wn + ni * 16 + l15;
                if (col >= HP) continue;
                size_t idx = (size_t)row * HP + col;
                float v = 0.0f;
                if (col < Nc) {
                    v = acc[mi][ni][r];
                    if constexpr (BIAS) v += bias[col];
                    if constexpr (ACT)  v = sspf(v);
                    if constexpr (ACCUM) v += unpackf(outP[idx]);
                }
                outP[idx] = packsplit(v);
            }
        }
    }
}

// Batched slab GEMM over all L layers stacked in M (1024 rows per layer;
// 128-row tiles never cross a layer). SHAREDA: A rows are (m % 1024).
template<bool SHAREDA, bool ACT>
__global__ __launch_bounds__(256, 2)
void gemm_tab(const int* __restrict__ A, int lda,
              const short* __restrict__ BhBase, const short* __restrict__ BlBase,
              int ldb, int bstride,
              const float* __restrict__ biasBase,
              int* __restrict__ outP,
              int Ma, int K, int Nc)
{
    const int NT = (Nc + TN - 1) / TN;
    const int f = blockIdx.x;
    const int xcd = f & 7, s = f >> 3;
    const int n0 = (s % NT) * TN;
    const int m0 = (xcd + 8 * (s / NT)) * TM;
    if (m0 >= Ma) return;

    const int layer = m0 >> 10;                       // 1024 rows per layer
    const int arow0 = SHAREDA ? (m0 & 1023) : m0;
    const short* __restrict__ Bh = BhBase + (size_t)layer * bstride;
    const short* __restrict__ Bl = BlBase + (size_t)layer * bstride;
    const float* __restrict__ bias = biasBase + (size_t)layer * H_DIM;

    __shared__ __align__(16) short As[2][TM * SA];
    __shared__ __align__(16) short Bs[2][TN * SA];

    const int tid = threadIdx.x;
    const int lane = tid & 63, wid = tid >> 6;
    const int wm = (wid >> 1) * 64, wn = (wid & 1) * 64;
    const int l15 = lane & 15, quad = lane >> 4;

    const int srow  = tid >> 1;
    const int shalf = (tid & 1) << 4;

    const int gn = min(n0 + srow, Nc - 1);
    const int*   aPtr  = A  + (size_t)(arow0 + srow) * lda + shalf;
    const short* bPtrH = Bh + (size_t)gn * ldb + shalf;
    const short* bPtrL = Bl + (size_t)gn * ldb + shalf;

    f32x4 acc[4][4];
    #pragma unroll
    for (int i = 0; i < 4; ++i)
        #pragma unroll
        for (int j = 0; j < 4; ++j)
            acc[i][j] = (f32x4){0.f, 0.f, 0.f, 0.f};

    int4 ra0, ra1, ra2, ra3;
    bf16x8 rbh0, rbh1, rbl0, rbl1;

    ra0 = *(const int4*)aPtr;       ra1 = *(const int4*)(aPtr + 4);
    ra2 = *(const int4*)(aPtr + 8); ra3 = *(const int4*)(aPtr + 12);
    rbh0 = *(const bf16x8*)bPtrH;   rbh1 = *(const bf16x8*)(bPtrH + 8);
    rbl0 = *(const bf16x8*)bPtrL;   rbl1 = *(const bf16x8*)(bPtrL + 8);
    aPtr += TK; bPtrH += TK; bPtrL += TK;

    for (int k0 = 0; k0 < K; k0 += TK) {
        {
            bf16x8 h01, l01, h23, l23;
            unpack8(ra0, ra1, h01, l01);
            unpack8(ra2, ra3, h23, l23);
            *(bf16x8*)&As[0][srow * SA + shalf]     = h01;
            *(bf16x8*)&As[0][srow * SA + shalf + 8] = h23;
            *(bf16x8*)&As[1][srow * SA + shalf]     = l01;
            *(bf16x8*)&As[1][srow * SA + shalf + 8] = l23;
            *(bf16x8*)&Bs[0][srow * SA + shalf]     = rbh0;
            *(bf16x8*)&Bs[0][srow * SA + shalf + 8] = rbh1;
            *(bf16x8*)&Bs[1][srow * SA + shalf]     = rbl0;
            *(bf16x8*)&Bs[1][srow * SA + shalf + 8] = rbl1;
        }
        __syncthreads();

        if (k0 + TK < K) {
            ra0 = *(const int4*)aPtr;       ra1 = *(const int4*)(aPtr + 4);
            ra2 = *(const int4*)(aPtr + 8); ra3 = *(const int4*)(aPtr + 12);
            rbh0 = *(const bf16x8*)bPtrH;   rbh1 = *(const bf16x8*)(bPtrH + 8);
            rbl0 = *(const bf16x8*)bPtrL;   rbl1 = *(const bf16x8*)(bPtrL + 8);
            aPtr += TK; bPtrH += TK; bPtrL += TK;
        }

        bf16x8 a_h[4], a_l[4], b_h[4], b_l[4];
        #pragma unroll
        for (int mi = 0; mi < 4; ++mi) {
            int row = wm + mi * 16 + l15;
            a_h[mi] = *(const bf16x8*)&As[0][row * SA + quad * 8];
            a_l[mi] = *(const bf16x8*)&As[1][row * SA + quad * 8];
        }
        #pragma unroll
        for (int ni = 0; ni < 4; ++ni) {
            int col = wn + ni * 16 + l15;
            b_h[ni] = *(const bf16x8*)&Bs[0][col * SA + quad * 8];
            b_l[ni] = *(const bf16x8*)&Bs[1][col * SA + quad * 8];
        }
        #pragma unroll
        for (int mi = 0; mi < 4; ++mi)
            #pragma unroll
            for (int ni = 0; ni < 4; ++ni) {
                acc[mi][ni] = __builtin_amdgcn_mfma_f32_16x16x32_bf16(
                    a_h[mi], b_h[ni], acc[mi][ni], 0, 0, 0);
                acc[mi][ni] = __builtin_amdgcn_mfma_f32_16x16x32_bf16(
                    a_h[mi], b_l[ni], acc[mi][ni], 0, 0, 0);
                acc[mi][ni] = __builtin_amdgcn_mfma_f32_16x16x32_bf16(
                    a_l[mi], b_h[ni], acc[mi][ni], 0, 0, 0);
            }
        __syncthreads();
    }

    #pragma unroll
    for (int mi = 0; mi < 4; ++mi) {
        #pragma unroll
        for (int r = 0; r < 4; ++r) {
            int row = m0 + wm + mi * 16 + quad * 4 + r;
            if (row >= Ma) continue;
            #pragma unroll
            for (int ni = 0; ni < 4; ++ni) {
                int col = n0 + wn + ni * 16 + l15;
                if (col >= HP) continue;
                float v = 0.0f;
                if (col < Nc) {
                    v = acc[mi][ni][r] + bias[col];
                    if constexpr (ACT) v = sspf(v);
                }
                outP[(size_t)row * HP + col] = packsplit(v);
            }
        }
    }
}

static inline dim3 mfma_grid(int Ma, int Nc) {
    int MB = (Ma + TM - 1) / TM;
    int NT = (Nc + TN - 1) / TN;
    int Ys = ((MB + 7) / 8) * 8;
    return dim3(Ys * NT);
}

// ------------------------------------------------- final pool matmul (tiny)
// pooled[128][600] @ pool_w[600][600] + b. Old 20-block gemm_k was pure
// latency (63us, VALU 1.1%). 256 blocks, 1 output col per thread, A row in
// LDS (broadcast reads), W rows L2-resident.
__global__ __launch_bounds__(320)
void pool_mm_k(const float* __restrict__ A, const float* __restrict__ W,
               const float* __restrict__ bias, float* __restrict__ out)
{
    __shared__ float arow[H_DIM];
    const int b = blockIdx.y;
    const int h = blockIdx.x;          // 0/1 -> col halves
    const int t = threadIdx.x;
    for (int k = t; k < H_DIM; k += 320)
        arow[k] = A[(size_t)b * H_DIM + k];
    __syncthreads();
    if (t >= 300) return;
    const int col = h * 300 + t;
    float s = 0.f;
    #pragma unroll 4
    for (int k = 0; k < H_DIM; ++k)
        s = fmaf(arow[k], W[(size_t)k * H_DIM + col], s);
    out[(size_t)b * H_DIM + col] = s + bias[col];
}

// ---------------------------------------------------------------- weight prep
__global__ __launch_bounds__(256)
void wts_w1_k(const float* __restrict__ w_all, short* __restrict__ oh,
              short* __restrict__ ol)
{
    __shared__ short th[64][65], tl[64][65];
    const int layer = blockIdx.z;
    const float* w = w_all + (size_t)layer * G_DIM * H_DIM;
    short* ohz = oh + (size_t)layer * H_DIM * 64;
    short* olz = ol + (size_t)layer * H_DIM * 64;
    const int n0 = blockIdx.y * 64;
    const int tid = threadIdx.x;
    #pragma unroll
    for (int p = 0; p < 4; ++p) {
        int k = p * 16 + (tid >> 4);
        int n4 = (tid & 15) << 2;
        float4 v = make_float4(0.f, 0.f, 0.f, 0.f);
        if (k < G_DIM && n0 + n4 + 3 < H_DIM)
            v = *(const float4*)(w + (size_t)k * H_DIM + n0 + n4);
        int px = packsplit(v.x), py = packsplit(v.y);
        int pz = packsplit(v.z), pw = packsplit(v.w);
        th[n4 + 0][k] = (short)(px >> 16); tl[n4 + 0][k] = (short)px;
        th[n4 + 1][k] = (short)(py >> 16); tl[n4 + 1][k] = (short)py;
        th[n4 + 2][k] = (short)(pz >> 16); tl[n4 + 2][k] = (short)pz;
        th[n4 + 3][k] = (short)(pw >> 16); tl[n4 + 3][k] = (short)pw;
    }
    __syncthreads();
    #pragma unroll
    for (int p = 0; p < 4; ++p) {
        int n = p * 16 + (tid >> 4);
        int k4 = (tid & 15) << 2;
        if (n0 + n >= H_DIM) continue;
        short4 sh = { th[n][k4], th[n][k4 + 1], th[n][k4 + 2], th[n][k4 + 3] };
        short4 sl = { tl[n][k4], tl[n][k4 + 1], tl[n][k4 + 2], tl[n][k4 + 3] };
        *(short4*)(ohz + (size_t)(n0 + n) * 64 + k4) = sh;
        *(short4*)(olz + (size_t)(n0 + n) * 64 + k4) = sl;
    }
}

__global__ __launch_bounds__(256)
void wts_big_k(const float* __restrict__ w2, const float* __restrict__ l1,
               const float* __restrict__ l2, const float* __restrict__ iw,
               short* __restrict__ oh2, short* __restrict__ ol2,
               short* __restrict__ oh1, short* __restrict__ ol1,
               short* __restrict__ ohl2, short* __restrict__ oll2,
               short* __restrict__ ohi, short* __restrict__ oli)
{
    __shared__ short th[64][65], tl[64][65];
    const int z = blockIdx.z, type = z / L_LAYERS, layer = z % L_LAYERS;
    const float* w; short* oh; short* ol;
    if (type == 0)      { w = w2; oh = oh2; ol = ol2; }
    else if (type == 1) { w = l1; oh = oh1; ol = ol1; }
    else if (type == 2) { w = l2; oh = ohl2; ol = oll2; }
    else                { w = iw; oh = ohi; ol = oli; }
    w  += (size_t)layer * H_DIM * H_DIM;
    oh += (size_t)layer * H_DIM * HP;
    ol += (size_t)layer * H_DIM * HP;
    const int k0 = blockIdx.x * 64, n0 = blockIdx.y * 64;
    const int tid = threadIdx.x;
    #pragma unroll
    for (int p = 0; p < 4; ++p) {
        int k = p * 16 + (tid >> 4);
        int n4 = (tid & 15) << 2;
        float4 v = make_float4(0.f, 0.f, 0.f, 0.f);
        if (k0 + k < H_DIM && n0 + n4 + 3 < H_DIM)
            v = *(const float4*)(w + (size_t)(k0 + k) * H_DIM + n0 + n4);
        int px = packsplit(v.x), py = packsplit(v.y);
        int pz = packsplit(v.z), pw = packsplit(v.w);
        th[n4 + 0][k] = (short)(px >> 16); tl[n4 + 0][k] = (short)px;
        th[n4 + 1][k] = (short)(py >> 16); tl[n4 + 1][k] = (short)py;
        th[n4 + 2][k] = (short)(pz >> 16); tl[n4 + 2][k] = (short)pz;
        th[n4 + 3][k] = (short)(pw >> 16); tl[n4 + 3][k] = (short)pw;
    }
    __syncthreads();
    #pragma unroll
    for (int p = 0; p < 4; ++p) {
        int n = p * 16 + (tid >> 4);
        int k4 = (tid & 15) << 2;
        if (n0 + n >= H_DIM || k0 + k4 > HP - 4) continue;
        short4 sh = { th[n][k4], th[n][k4 + 1], th[n][k4 + 2], th[n][k4 + 3] };
        short4 sl = { tl[n][k4], tl[n][k4 + 1], tl[n][k4 + 2], tl[n][k4 + 3] };
        *(short4*)(oh + (size_t)(n0 + n) * HP + k0 + k4) = sh;
        *(short4*)(ol + (size_t)(n0 + n) * HP + k0 + k4) = sl;
    }
}

// ---------------------------------------------------------------- helpers
__global__ __launch_bounds__(256)
void init_h_k(const int* __restrict__ z, const float* __restrict__ emb,
              int* __restrict__ hP)
{
    int t = blockIdx.x * 256 + threadIdx.x;
    const int QC = HP / 4;   // 152
    if (t >= N_ATOMS * QC) return;
    int i = t / QC;
    int q = (t - i * QC) << 2;
    size_t idx = (size_t)i * HP + q;
    if (q < H_DIM) {
        float4 v = *(const float4*)(emb + (size_t)z[i] * H_DIM + q);
        *(int4*)(hP + idx) = make_int4(packsplit(v.x), packsplit(v.y),
                                       packsplit(v.z), packsplit(v.w));
    } else {
        *(int4*)(hP + idx) = make_int4(0, 0, 0, 0);
    }
}

// per-edge record: {src*HP, i0*HP, a = C - f*C, b = f*C}
__global__ __launch_bounds__(256)
void edge_geom_k(const float* __restrict__ pos, const int* __restrict__ src,
                 const int* __restrict__ dst, float4* __restrict__ einfo)
{
    int e = blockIdx.x * 256 + threadIdx.x;
    if (e >= E_EDGES) return;
    int s = src[e], d0 = dst[e];
    float dx = pos[s * 3 + 0] - pos[d0 * 3 + 0];
    float dy = pos[s * 3 + 1] - pos[d0 * 3 + 1];
    float dz = pos[s * 3 + 2] - pos[d0 * 3 + 2];
    float dist = sqrtf(dx * dx + dy * dy + dz * dz + 1e-12f);
    float cc = 0.5f * (cosf(dist * 0.31415926535f) + 1.0f);
    float u = dist * ((float)(M_TAB - 1) / DMAX);
    u = fminf(fmaxf(u, 0.0f), (float)(M_TAB - 1) - 0.001f);
    int i0 = (int)u;
    float fc = (u - (float)i0) * cc;
    einfo[e] = make_float4(__int_as_float(s * HP),
                           __int_as_float(i0 * HP),
                           cc - fc, fc);
}

__global__ __launch_bounds__(256)
void rbf_tab_k(int* __restrict__ rtabP)
{
    int t = blockIdx.x * 256 + threadIdx.x;
    if (t >= M_TAB * 64) return;
    int i = t >> 6, g = t & 63;
    float v = 0.0f;
    if (g < G_DIM) {
        float dg  = (float)i * (DMAX / (float)(M_TAB - 1));
        float off = (float)g * (10.0f / 49.0f);
        float x = dg - off;
        const float coeff = -0.5f * (49.0f / 10.0f) * (49.0f / 10.0f);
        v = expf(coeff * x * x);
    }
    rtabP[t] = packsplit(v);
}

// ---------------------------------------------------------------- CSR build
__global__ __launch_bounds__(256)
void hist_k(const int* __restrict__ dst, int* __restrict__ deg)
{
    int e = blockIdx.x * 256 + threadIdx.x;
    if (e >= E_EDGES) return;
    atomicAdd(&deg[dst[e]], 1);
}

__global__ __launch_bounds__(1024)
void scan_k(const int* __restrict__ deg, int* __restrict__ rowptr)
{
    __shared__ int sums[1024];
    int tid = threadIdx.x;
    const int CHUNK = (N_ATOMS + 1023) / 1024;
    int base = tid * CHUNK;
    int local[16];
    int s = 0;
    #pragma unroll
    for (int c = 0; c < 16; ++c) {
        if (c >= CHUNK) break;
        int idx = base + c;
        local[c] = s;
        s += (idx < N_ATOMS) ? deg[idx] : 0;
    }
    sums[tid] = s;
    __syncthreads();
    for (int off = 1; off < 1024; off <<= 1) {
        int v = (tid >= off) ? sums[tid - off] : 0;
        __syncthreads();
        sums[tid] += v;
        __syncthreads();
    }
    int prefix = (tid > 0) ? sums[tid - 1] : 0;
    #pragma unroll
    for (int c = 0; c < 16; ++c) {
        if (c >= CHUNK) break;
        int idx = base + c;
        if (idx <= N_ATOMS) rowptr[idx] = prefix + local[c];
    }
    if (tid == 1023) rowptr[N_ATOMS] = sums[1023];
}

__global__ __launch_bounds__(256)
void fill_k(const int* __restrict__ dst, const float4* __restrict__ einfo,
            const int* __restrict__ rowptr, int* __restrict__ cursor,
            float4* __restrict__ esorted)
{
    int e = blockIdx.x * 256 + threadIdx.x;
    if (e >= E_EDGES) return;
    int d0 = dst[e];
    int pos = rowptr[d0] + atomicAdd(&cursor[d0], 1);
    esorted[pos] = einfo[e];
}

// molecule boundaries via binary search over the SORTED batch array
__global__ __launch_bounds__(256)
void bounds_k(const int* __restrict__ batch, int* __restrict__ mrow)
{
    int b = threadIdx.x;
    if (b > B_MOLS) return;
    int lo = 0, hi = N_ATOMS;
    while (lo < hi) {
        int mid = (lo + hi) >> 1;
        if (batch[mid] < b) lo = mid + 1; else hi = mid;
    }
    mrow[b] = lo;
}

// ---------------------------------------------------------------- gather
__device__ __forceinline__ void gacc(float4& acc, const int* yP, const int* wtP,
                                     const float4& ei, int q)
{
    int srow = __float_as_int(ei.x);
    int wrow = __float_as_int(ei.y);
    float a = ei.z, b = ei.w;
    int4 yv = *(const int4*)(yP + srow + q);
    int4 w0 = *(const int4*)(wtP + wrow + q);
    int4 w1 = *(const int4*)(wtP + wrow + HP + q);
    acc.x += unpackf(yv.x) * (a * unpackf(w0.x) + b * unpackf(w1.x));
    acc.y += unpackf(yv.y) * (a * unpackf(w0.y) + b * unpackf(w1.y));
    acc.z += unpackf(yv.z) * (a * unpackf(w0.z) + b * unpackf(w1.z));
    acc.w += unpackf(yv.w) * (a * unpackf(w0.w) + b * unpackf(w1.w));
}

__global__ __launch_bounds__(256)
void gather_k(const int* __restrict__ yP, const int* __restrict__ wtP,
              const int* __restrict__ rowptr, const float4* __restrict__ esorted,
              int* __restrict__ aggP)
{
    int t = blockIdx.x * 256 + threadIdx.x;
    const int QC = HP / 4;   // 152
    if (t >= N_ATOMS * QC) return;
    int i = t / QC;
    int q = (t - i * QC) << 2;
    size_t idx = (size_t)i * HP + q;
    if (q >= H_DIM) { *(int4*)(aggP + idx) = make_int4(0, 0, 0, 0); return; }
    int j0 = rowptr[i], j1 = rowptr[i + 1];
    float4 a0 = make_float4(0.f, 0.f, 0.f, 0.f);
    float4 a1 = make_float4(0.f, 0.f, 0.f, 0.f);
    int j = j0;
    for (; j + 2 <= j1; j += 2) {
        float4 e0 = esorted[j], e1 = esorted[j + 1];
        gacc(a0, yP, wtP, e0, q);
        gacc(a1, yP, wtP, e1, q);
    }
    if (j < j1) gacc(a0, yP, wtP, esorted[j], q);
    a0.x += a1.x; a0.y += a1.y; a0.z += a1.z; a0.w += a1.w;
    *(int4*)(aggP + idx) = make_int4(packsplit(a0.x), packsplit(a0.y),
                                     packsplit(a0.z), packsplit(a0.w));
}

// ---------------------------------------------------------------- pool (segment mean, no atomics)
__global__ __launch_bounds__(256)
void pool_seg_k(const int* __restrict__ hP, const int* __restrict__ mrow,
                float* __restrict__ pooled)
{
    int b = blockIdx.x;
    int t = threadIdx.x;
    if (t >= 150) return;               // cols 600..607 are pad
    int q = t << 2;
    int a = mrow[b], a1 = mrow[b + 1];
    float cnt = (float)(a1 - a);
    float4 s0 = make_float4(0.f, 0.f, 0.f, 0.f);
    float4 s1 = make_float4(0.f, 0.f, 0.f, 0.f);
    for (; a + 2 <= a1; a += 2) {
        int4 p0 = *(const int4*)(hP + (size_t)a * HP + q);
        int4 p1 = *(const int4*)(hP + (size_t)(a + 1) * HP + q);
        s0.x += unpackf(p0.x); s0.y += unpackf(p0.y);
        s0.z += unpackf(p0.z); s0.w += unpackf(p0.w);
        s1.x += unpackf(p1.x); s1.y += unpackf(p1.y);
        s1.z += unpackf(p1.z); s1.w += unpackf(p1.w);
    }
    if (a < a1) {
        int4 p0 = *(const int4*)(hP + (size_t)a * HP + q);
        s0.x += unpackf(p0.x); s0.y += unpackf(p0.y);
        s0.z += unpackf(p0.z); s0.w += unpackf(p0.w);
    }
    float inv = 1.0f / fmaxf(cnt, 1.0f);
    float4 o = make_float4((s0.x + s1.x) * inv, (s0.y + s1.y) * inv,
                           (s0.z + s1.z) * inv, (s0.w + s1.w) * inv);
    *(float4*)(pooled + (size_t)b * H_DIM + q) = o;
}

// ---------------------------------------------------------------- launch
extern "C" void kernel_launch(void* const* d_in, const int* in_sizes, int n_in,
                              void* d_out, int out_size, void* d_ws, size_t ws_size,
                              hipStream_t stream)
{
    const int*   z      = (const int*)  d_in[0];
    const float* pos    = (const float*)d_in[1];
    const int*   batch  = (const int*)  d_in[2];
    const int*   eidx   = (const int*)  d_in[3];
    const float* emb    = (const float*)d_in[4];
    const float* mlp_w1 = (const float*)d_in[5];
    const float* mlp_b1 = (const float*)d_in[6];
    const float* mlp_w2 = (const float*)d_in[7];
    const float* mlp_b2 = (const float*)d_in[8];
    const float* lin1_w = (const float*)d_in[9];
    const float* lin2_w = (const float*)d_in[10];
    const float* lin2_b = (const float*)d_in[11];
    const float* intw   = (const float*)d_in[12];
    const float* intb   = (const float*)d_in[13];
    const float* poolw  = (const float*)d_in[14];
    const float* poolb  = (const float*)d_in[15];

    float* ws = (float*)d_ws;
    const size_t NHP = (size_t)N_ATOMS * HP;       // 6,080,000
    const size_t TABALL = (size_t)L_LAYERS * M_TAB * HP;   // 3,735,552

    int*   hP    = (int*)ws;                       // NHP
    int*   y1P   = (int*)(ws + NHP);               // NHP; aliases tP, ttabA
    int*   tP    = y1P;
    int*   ttabA = y1P;                            // prep-time alias (3.7M <= NHP)
    int*   aggP  = (int*)(ws + 2 * NHP);           // NHP
    // aggP region aliases — ONLY prep-phase data that's dead before gather:
    float4* einfo  = (float4*)aggP;                          // 256,000 f
    int*    deg    = (int*)((float*)aggP + 300000);          // 10,000
    int*    cursor = (int*)((float*)aggP + 310000);          // 10,000
    int*   wtabA = (int*)(ws + 3 * NHP);           // TABALL (persistent)
    int*   rtabP = (int*)(ws + 3 * NHP + TABALL);  // M_TAB*64 = 65,536
    short* wtH   = (short*)(ws + 3 * NHP + TABALL + (size_t)M_TAB * 64);
    short* wtL   = wtH + 8985600;
    // persistent tail (NOT aliased): esorted, pooled, rowptr, mrow
    float*  tailF   = (float*)(wtL + 8985600);
    float4* esorted = (float4*)tailF;                        // 256,000 f
    float*  pooled  = tailF + 256000;                        // 76,800 f
    int*    rowptr  = (int*)(tailF + 332800);                // 10,001
    int*    mrow    = rowptr + 10001;                        // 129

    short* w1t_h = wtH;                       short* w1t_l = wtL;
    short* w2t_h = wtH + 230400;              short* w2t_l = wtL + 230400;
    short* l1t_h = w2t_h + 6 * 600 * HP;      short* l1t_l = w2t_l + 6 * 600 * HP;
    short* l2t_h = l1t_h + 6 * 600 * HP;      short* l2t_l = l1t_l + 6 * 600 * HP;
    short* int_h = l2t_h + 6 * 600 * HP;      short* int_l = l2t_l + 6 * 600 * HP;

    const int* src = eidx;
    const int* dst = eidx + E_EDGES;

    const dim3 blk(256);
    const int QC = HP / 4;
    const dim3 gN   = mfma_grid(N_ATOMS, H_DIM);            // 400
    const dim3 gTab = mfma_grid(L_LAYERS * M_TAB, H_DIM);   // 240

    // ---- one-time prep (einfo/deg/cursor alias aggP: dead before gather)
    edge_geom_k<<<(E_EDGES + 255) / 256, blk, 0, stream>>>(pos, src, dst, einfo);
    hipMemsetAsync(deg, 0, 2 * N_ATOMS * sizeof(int), stream);
    hist_k <<<(E_EDGES + 255) / 256, blk, 0, stream>>>(dst, deg);
    scan_k <<<1, 1024, 0, stream>>>(deg, rowptr);
    fill_k <<<(E_EDGES + 255) / 256, blk, 0, stream>>>(dst, einfo, rowptr, cursor, esorted);
    bounds_k <<<1, 256, 0, stream>>>(batch, mrow);
    init_h_k <<<(N_ATOMS * QC + 255) / 256, blk, 0, stream>>>(z, emb, hP);
    rbf_tab_k<<<(M_TAB * 64 + 255) / 256,   blk, 0, stream>>>(rtabP);
    wts_w1_k  <<<dim3(1, 10, 6),   blk, 0, stream>>>(mlp_w1, w1t_h, w1t_l);
    wts_big_k <<<dim3(10, 10, 24), blk, 0, stream>>>(
        mlp_w2, lin1_w, lin2_w, intw,
        w2t_h, w2t_l, l1t_h, l1t_l, l2t_h, l2t_l, int_h, int_l);

    // ---- all 6 layers' filter tables in 2 batched slab GEMMs
    gemm_tab<true, true><<<gTab, blk, 0, stream>>>(
        rtabP, 64, w1t_h, w1t_l, 64, 600 * 64, mlp_b1,
        ttabA, L_LAYERS * M_TAB, 64, H_DIM);
    gemm_tab<false, false><<<gTab, blk, 0, stream>>>(
        ttabA, HP, w2t_h, w2t_l, HP, 600 * HP, mlp_b2,
        wtabA, L_LAYERS * M_TAB, HP, H_DIM);

    for (int k = 0; k < L_LAYERS; ++k) {
        const float* l2b = lin2_b + (size_t)k * H_DIM;
        const float* ib  = intb   + (size_t)k * H_DIM;
        const short* l1h = l1t_h + (size_t)k * H_DIM * HP;
        const short* l1l = l1t_l + (size_t)k * H_DIM * HP;
        const short* l2h = l2t_h + (size_t)k * H_DIM * HP;
        const short* l2l = l2t_l + (size_t)k * H_DIM * HP;
        const short* ih  = int_h + (size_t)k * H_DIM * HP;
        const short* il  = int_l + (size_t)k * H_DIM * HP;
        const int*   wtP = wtabA + (size_t)k * M_TAB * HP;

        // y1P = packsplit(h @ lin1)
        gemm_mfma<false, false, false><<<gN, blk, 0, stream>>>(
            hP, HP, l1h, l1l, HP, nullptr, y1P, N_ATOMS, HP, H_DIM);
        // aggP = packsplit(CSR-gather(y1 * W(d) * C))
        gather_k<<<(N_ATOMS * QC + 255) / 256, blk, 0, stream>>>(
            y1P, wtP, rowptr, esorted, aggP);
        // tP = packsplit(ssp(agg @ lin2 + b))   (aliases y1P)
        gemm_mfma<true, true, false><<<gN, blk, 0, stream>>>(
            aggP, HP, l2h, l2l, HP, l2b, tP, N_ATOMS, HP, H_DIM);
        // hP = packsplit(unpack(hP) + t @ int_w + ib)
        gemm_mfma<true, false, true><<<gN, blk, 0, stream>>>(
            tP, HP, ih, il, HP, ib, hP, N_ATOMS, HP, H_DIM);
    }

    // segment-mean pool (sorted batch, no atomics), then out = pooled @ pool_w + b
    pool_seg_k<<<B_MOLS, blk, 0, stream>>>(hP, mrow, pooled);
    pool_mm_k<<<dim3(2, B_MOLS), dim3(320), 0, stream>>>(
        pooled, poolw, poolb, (float*)d_out);
}

// Round 2
// 1238.217 us; speedup vs baseline: 1.1823x; 1.1823x over previous
//
#include <hip/hip_runtime.h>
#include <math.h>

// SchNet forward, MI355X. Round 13 = revert r12's 128x128 tiles (regression:
// grid 400 blocks = 1.56/CU -> 2-round tail imbalance, occupancy 49%->~25%,
// gemm 63->~70us) back to r11's 64x64 / 1600-block / 6-per-CU shape, keeping
// only the measured fix for r0's 7.6M SQ_LDS_BANK_CONFLICT:
//  - staging LDS writes were b64 at byte slot (10*row+2*q) mod 16 = always
//    even -> 2x write serialization. Now each thread writes one bf16x8
//    (b128) per array at slot (5*row+q) mod 8 = perfectly balanced ->
//    conflict-free. Same thread mapping, same data placement, bit-identical.
//  - B staging loads widened to bf16x8 (one 16B load instead of 2x short4).
//  - pool matmul: r12's pool_mm_k was latency-bound (74us, VALU 3%, 256
//    blocks, 600-deep serial fmaf chain). New pool_mm2_k: 1280 blocks,
//    4-way K-split per column + LDS reduce (chain 150 deep, 5 blocks/CU).
// Stack: segment pool, batched tab GEMMs, packed bf16 hi/lo residual,
// 64x64 tiles lb(256,6), HP=608 sector alignment, XCD swizzle, CSR gather,
// filter-table + lerp (absmax 2.4e-4 vs 1.44e-3 budget).

#define N_ATOMS 10000
#define E_EDGES 64000
#define B_MOLS  128
#define H_DIM   600
#define HP      608            // padded leading dim (608*4B = 38 sectors)
#define G_DIM   50
#define L_LAYERS 6
#define M_TAB   1024
#define DMAX    8.67f
#define LOG2C   0.69314718056f

#define TM 64
#define TN 64
#define TK 32
#define SA 40          // LDS row stride in shorts (80B rows)

typedef __attribute__((ext_vector_type(8))) short bf16x8;
typedef __attribute__((ext_vector_type(4))) float f32x4;

__device__ __forceinline__ float sspf(float x) {
    return fmaxf(x, 0.0f) + log1pf(expf(-fabsf(x))) - LOG2C;
}
__device__ __forceinline__ short f2bf(float x) {
    unsigned u = __float_as_uint(x);
    unsigned r = (u + 0x7FFF + ((u >> 16) & 1)) >> 16;   // RNE
    return (short)r;
}
__device__ __forceinline__ float bf2f(short h) {
    return __uint_as_float(((unsigned)(unsigned short)h) << 16);
}
__device__ __forceinline__ int packsplit(float x) {
    short hi = f2bf(x);
    short lo = f2bf(x - bf2f(hi));
    return ((int)hi << 16) | ((int)lo & 0xffff);
}
__device__ __forceinline__ float unpackf(int p) {
    float fh = __uint_as_float((unsigned)p & 0xffff0000u);
    float fl = __uint_as_float(((unsigned)p) << 16);
    return fh + fl;
}

// 8 packed ints -> 8 hi shorts + 8 lo shorts (one b128 write each)
__device__ __forceinline__ void unpack8(const int4& p0, const int4& p1,
                                        bf16x8& hi, bf16x8& lo)
{
    hi = (bf16x8){ (short)(p0.x >> 16), (short)(p0.y >> 16),
                   (short)(p0.z >> 16), (short)(p0.w >> 16),
                   (short)(p1.x >> 16), (short)(p1.y >> 16),
                   (short)(p1.z >> 16), (short)(p1.w >> 16) };
    lo = (bf16x8){ (short)p0.x, (short)p0.y, (short)p0.z, (short)p0.w,
                   (short)p1.x, (short)p1.y, (short)p1.z, (short)p1.w };
}

// ---------------------------------------------------------------- MFMA GEMM
// outP = packsplit(op(A @ B + bias [+ unpack(outP)])). A: packed int [Ma][lda]
// (zero-padded cols). B: TRANSPOSED pre-split bf16 hi/lo [Nc][ldb] (zero-
// padded k). K % 32 == 0. Output ld = HP, pad cols 0. 1D grid, XCD swizzle.
// Staging rows clamped (no per-chunk guards); OOB contributions are masked
// by the epilogue (rows >= Ma skipped, cols >= Nc written 0).
template<bool BIAS, bool ACT, bool ACCUM>
__global__ __launch_bounds__(256, 6)
void gemm_mfma(const int* __restrict__ A, int lda,
               const short* __restrict__ Bh, const short* __restrict__ Bl, int ldb,
               const float* __restrict__ bias,
               int* __restrict__ outP,
               int Ma, int K, int Nc)
{
    const int NT = (Nc + TN - 1) / TN;
    const int f = blockIdx.x;
    const int xcd = f & 7, s = f >> 3;
    const int n0 = (s % NT) * TN;
    const int m0 = (xcd + 8 * (s / NT)) * TM;
    if (m0 >= Ma) return;

    __shared__ __align__(16) short As[2][TM * SA];
    __shared__ __align__(16) short Bs[2][TN * SA];

    const int tid = threadIdx.x;
    const int lane = tid & 63, wid = tid >> 6;
    const int wm = (wid >> 1) * 32, wn = (wid & 1) * 32;
    const int l15 = lane & 15, quad = lane >> 4;
    const int srow = tid >> 2;          // 0..63
    const int skk  = (tid & 3) << 3;    // 0,8,16,24

    // clamped staging pointers; advanced by TK per chunk
    const int gm = min(m0 + srow, Ma - 1);
    const int gn = min(n0 + srow, Nc - 1);
    const int*   aPtr  = A  + (size_t)gm * lda + skk;
    const short* bPtrH = Bh + (size_t)gn * ldb + skk;
    const short* bPtrL = Bl + (size_t)gn * ldb + skk;

    f32x4 acc[2][2];
    #pragma unroll
    for (int i = 0; i < 2; ++i)
        #pragma unroll
        for (int j = 0; j < 2; ++j)
            acc[i][j] = (f32x4){0.f, 0.f, 0.f, 0.f};

    int4 ra0, ra1;
    bf16x8 rbh, rbl;

    // prefetch chunk 0
    ra0 = *(const int4*)aPtr; ra1 = *(const int4*)(aPtr + 4);
    rbh = *(const bf16x8*)bPtrH;
    rbl = *(const bf16x8*)bPtrL;
    aPtr += TK; bPtrH += TK; bPtrL += TK;

    for (int k0 = 0; k0 < K; k0 += TK) {
        {
            bf16x8 hi, lo;
            unpack8(ra0, ra1, hi, lo);
            *(bf16x8*)&As[0][srow * SA + skk] = hi;
            *(bf16x8*)&As[1][srow * SA + skk] = lo;
            *(bf16x8*)&Bs[0][srow * SA + skk] = rbh;
            *(bf16x8*)&Bs[1][srow * SA + skk] = rbl;
        }
        __syncthreads();

        if (k0 + TK < K) {
            ra0 = *(const int4*)aPtr; ra1 = *(const int4*)(aPtr + 4);
            rbh = *(const bf16x8*)bPtrH;
            rbl = *(const bf16x8*)bPtrL;
            aPtr += TK; bPtrH += TK; bPtrL += TK;
        }

        bf16x8 a_h[2], a_l[2], b_h[2], b_l[2];
        #pragma unroll
        for (int mi = 0; mi < 2; ++mi) {
            int row = wm + mi * 16 + l15;
            a_h[mi] = *(const bf16x8*)&As[0][row * SA + quad * 8];
            a_l[mi] = *(const bf16x8*)&As[1][row * SA + quad * 8];
        }
        #pragma unroll
        for (int ni = 0; ni < 2; ++ni) {
            int col = wn + ni * 16 + l15;
            b_h[ni] = *(const bf16x8*)&Bs[0][col * SA + quad * 8];
            b_l[ni] = *(const bf16x8*)&Bs[1][col * SA + quad * 8];
        }

        #pragma unroll
        for (int mi = 0; mi < 2; ++mi)
            #pragma unroll
            for (int ni = 0; ni < 2; ++ni) {
                acc[mi][ni] = __builtin_amdgcn_mfma_f32_16x16x32_bf16(
                    a_h[mi], b_h[ni], acc[mi][ni], 0, 0, 0);
                acc[mi][ni] = __builtin_amdgcn_mfma_f32_16x16x32_bf16(
                    a_h[mi], b_l[ni], acc[mi][ni], 0, 0, 0);
                acc[mi][ni] = __builtin_amdgcn_mfma_f32_16x16x32_bf16(
                    a_l[mi], b_h[ni], acc[mi][ni], 0, 0, 0);
            }
        __syncthreads();
    }

    #pragma unroll
    for (int mi = 0; mi < 2; ++mi) {
        #pragma unroll
        for (int r = 0; r < 4; ++r) {
            int row = m0 + wm + mi * 16 + quad * 4 + r;
            if (row >= Ma) continue;
            #pragma unroll
            for (int ni = 0; ni < 2; ++ni) {
                int col = n0 + wn + ni * 16 + l15;
                if (col >= HP) continue;
                size_t idx = (size_t)row * HP + col;
                float v = 0.0f;
                if (col < Nc) {
                    v = acc[mi][ni][r];
                    if constexpr (BIAS) v += bias[col];
                    if constexpr (ACT)  v = sspf(v);
                    if constexpr (ACCUM) v += unpackf(outP[idx]);
                }
                outP[idx] = packsplit(v);
            }
        }
    }
}

// Batched slab GEMM over all L layers stacked in M (1024 rows per layer).
// SHAREDA: A rows are (m % 1024). Same staging scheme.
template<bool SHAREDA, bool ACT>
__global__ __launch_bounds__(256, 6)
void gemm_tab(const int* __restrict__ A, int lda,
              const short* __restrict__ BhBase, const short* __restrict__ BlBase,
              int ldb, int bstride,
              const float* __restrict__ biasBase,
              int* __restrict__ outP,
              int Ma, int K, int Nc)
{
    const int NT = (Nc + TN - 1) / TN;
    const int f = blockIdx.x;
    const int xcd = f & 7, s = f >> 3;
    const int n0 = (s % NT) * TN;
    const int m0 = (xcd + 8 * (s / NT)) * TM;
    if (m0 >= Ma) return;

    const int layer = m0 >> 10;                       // 1024 rows per layer
    const int arow0 = SHAREDA ? (m0 & 1023) : m0;
    const short* __restrict__ Bh = BhBase + (size_t)layer * bstride;
    const short* __restrict__ Bl = BlBase + (size_t)layer * bstride;
    const float* __restrict__ bias = biasBase + (size_t)layer * H_DIM;

    __shared__ __align__(16) short As[2][TM * SA];
    __shared__ __align__(16) short Bs[2][TN * SA];

    const int tid = threadIdx.x;
    const int lane = tid & 63, wid = tid >> 6;
    const int wm = (wid >> 1) * 32, wn = (wid & 1) * 32;
    const int l15 = lane & 15, quad = lane >> 4;
    const int srow = tid >> 2;
    const int skk  = (tid & 3) << 3;

    const int gn = min(n0 + srow, Nc - 1);
    const int*   aPtr  = A  + (size_t)(arow0 + srow) * lda + skk;
    const short* bPtrH = Bh + (size_t)gn * ldb + skk;
    const short* bPtrL = Bl + (size_t)gn * ldb + skk;

    f32x4 acc[2][2];
    #pragma unroll
    for (int i = 0; i < 2; ++i)
        #pragma unroll
        for (int j = 0; j < 2; ++j)
            acc[i][j] = (f32x4){0.f, 0.f, 0.f, 0.f};

    int4 ra0, ra1;
    bf16x8 rbh, rbl;

    ra0 = *(const int4*)aPtr; ra1 = *(const int4*)(aPtr + 4);
    rbh = *(const bf16x8*)bPtrH;
    rbl = *(const bf16x8*)bPtrL;
    aPtr += TK; bPtrH += TK; bPtrL += TK;

    for (int k0 = 0; k0 < K; k0 += TK) {
        {
            bf16x8 hi, lo;
            unpack8(ra0, ra1, hi, lo);
            *(bf16x8*)&As[0][srow * SA + skk] = hi;
            *(bf16x8*)&As[1][srow * SA + skk] = lo;
            *(bf16x8*)&Bs[0][srow * SA + skk] = rbh;
            *(bf16x8*)&Bs[1][srow * SA + skk] = rbl;
        }
        __syncthreads();

        if (k0 + TK < K) {
            ra0 = *(const int4*)aPtr; ra1 = *(const int4*)(aPtr + 4);
            rbh = *(const bf16x8*)bPtrH;
            rbl = *(const bf16x8*)bPtrL;
            aPtr += TK; bPtrH += TK; bPtrL += TK;
        }

        bf16x8 a_h[2], a_l[2], b_h[2], b_l[2];
        #pragma unroll
        for (int mi = 0; mi < 2; ++mi) {
            int row = wm + mi * 16 + l15;
            a_h[mi] = *(const bf16x8*)&As[0][row * SA + quad * 8];
            a_l[mi] = *(const bf16x8*)&As[1][row * SA + quad * 8];
        }
        #pragma unroll
        for (int ni = 0; ni < 2; ++ni) {
            int col = wn + ni * 16 + l15;
            b_h[ni] = *(const bf16x8*)&Bs[0][col * SA + quad * 8];
            b_l[ni] = *(const bf16x8*)&Bs[1][col * SA + quad * 8];
        }
        #pragma unroll
        for (int mi = 0; mi < 2; ++mi)
            #pragma unroll
            for (int ni = 0; ni < 2; ++ni) {
                acc[mi][ni] = __builtin_amdgcn_mfma_f32_16x16x32_bf16(
                    a_h[mi], b_h[ni], acc[mi][ni], 0, 0, 0);
                acc[mi][ni] = __builtin_amdgcn_mfma_f32_16x16x32_bf16(
                    a_h[mi], b_l[ni], acc[mi][ni], 0, 0, 0);
                acc[mi][ni] = __builtin_amdgcn_mfma_f32_16x16x32_bf16(
                    a_l[mi], b_h[ni], acc[mi][ni], 0, 0, 0);
            }
        __syncthreads();
    }

    #pragma unroll
    for (int mi = 0; mi < 2; ++mi) {
        #pragma unroll
        for (int r = 0; r < 4; ++r) {
            int row = m0 + wm + mi * 16 + quad * 4 + r;
            if (row >= Ma) continue;
            #pragma unroll
            for (int ni = 0; ni < 2; ++ni) {
                int col = n0 + wn + ni * 16 + l15;
                if (col >= HP) continue;
                float v = 0.0f;
                if (col < Nc) {
                    v = acc[mi][ni][r] + bias[col];
                    if constexpr (ACT) v = sspf(v);
                }
                outP[(size_t)row * HP + col] = packsplit(v);
            }
        }
    }
}

static inline dim3 mfma_grid(int Ma, int Nc) {
    int MB = (Ma + TM - 1) / TM;
    int NT = (Nc + TN - 1) / TN;
    int Ys = ((MB + 7) / 8) * 8;
    return dim3(Ys * NT);
}

// ------------------------------------------------- final pool matmul (tiny)
// pooled[128][600] @ pool_w[600][600] + b. 4-way K-split per column + LDS
// reduce: 1280 blocks (5/CU), serial chain 150 deep instead of 600.
__global__ __launch_bounds__(256)
void pool_mm2_k(const float* __restrict__ A, const float* __restrict__ W,
                const float* __restrict__ bias, float* __restrict__ out)
{
    __shared__ float arow[H_DIM];
    __shared__ float red[4][64];
    const int b = blockIdx.y;
    const int ct = blockIdx.x;             // 10 tiles of 64 cols
    const int t = threadIdx.x;
    const int ci = t & 63, kq = t >> 6;    // wave-uniform K quarter
    for (int k = t; k < H_DIM; k += 256)
        arow[k] = A[(size_t)b * H_DIM + k];
    __syncthreads();
    const int col = min(ct * 64 + ci, H_DIM - 1);   // clamp; store guarded
    const float* wp = W + (size_t)(kq * 150) * H_DIM + col;
    float s = 0.f;
    #pragma unroll 6
    for (int k = 0; k < 150; ++k)
        s = fmaf(arow[kq * 150 + k], wp[(size_t)k * H_DIM], s);
    red[kq][ci] = s;
    __syncthreads();
    if (kq == 0) {
        int c = ct * 64 + ci;
        if (c < H_DIM)
            out[(size_t)b * H_DIM + c] =
                red[0][ci] + red[1][ci] + red[2][ci] + red[3][ci] + bias[c];
    }
}

// ---------------------------------------------------------------- weight prep
__global__ __launch_bounds__(256)
void wts_w1_k(const float* __restrict__ w_all, short* __restrict__ oh,
              short* __restrict__ ol)
{
    __shared__ short th[64][65], tl[64][65];
    const int layer = blockIdx.z;
    const float* w = w_all + (size_t)layer * G_DIM * H_DIM;
    short* ohz = oh + (size_t)layer * H_DIM * 64;
    short* olz = ol + (size_t)layer * H_DIM * 64;
    const int n0 = blockIdx.y * 64;
    const int tid = threadIdx.x;
    #pragma unroll
    for (int p = 0; p < 4; ++p) {
        int k = p * 16 + (tid >> 4);
        int n4 = (tid & 15) << 2;
        float4 v = make_float4(0.f, 0.f, 0.f, 0.f);
        if (k < G_DIM && n0 + n4 + 3 < H_DIM)
            v = *(const float4*)(w + (size_t)k * H_DIM + n0 + n4);
        int px = packsplit(v.x), py = packsplit(v.y);
        int pz = packsplit(v.z), pw = packsplit(v.w);
        th[n4 + 0][k] = (short)(px >> 16); tl[n4 + 0][k] = (short)px;
        th[n4 + 1][k] = (short)(py >> 16); tl[n4 + 1][k] = (short)py;
        th[n4 + 2][k] = (short)(pz >> 16); tl[n4 + 2][k] = (short)pz;
        th[n4 + 3][k] = (short)(pw >> 16); tl[n4 + 3][k] = (short)pw;
    }
    __syncthreads();
    #pragma unroll
    for (int p = 0; p < 4; ++p) {
        int n = p * 16 + (tid >> 4);
        int k4 = (tid & 15) << 2;
        if (n0 + n >= H_DIM) continue;
        short4 sh = { th[n][k4], th[n][k4 + 1], th[n][k4 + 2], th[n][k4 + 3] };
        short4 sl = { tl[n][k4], tl[n][k4 + 1], tl[n][k4 + 2], tl[n][k4 + 3] };
        *(short4*)(ohz + (size_t)(n0 + n) * 64 + k4) = sh;
        *(short4*)(olz + (size_t)(n0 + n) * 64 + k4) = sl;
    }
}

__global__ __launch_bounds__(256)
void wts_big_k(const float* __restrict__ w2, const float* __restrict__ l1,
               const float* __restrict__ l2, const float* __restrict__ iw,
               short* __restrict__ oh2, short* __restrict__ ol2,
               short* __restrict__ oh1, short* __restrict__ ol1,
               short* __restrict__ ohl2, short* __restrict__ oll2,
               short* __restrict__ ohi, short* __restrict__ oli)
{
    __shared__ short th[64][65], tl[64][65];
    const int z = blockIdx.z, type = z / L_LAYERS, layer = z % L_LAYERS;
    const float* w; short* oh; short* ol;
    if (type == 0)      { w = w2; oh = oh2; ol = ol2; }
    else if (type == 1) { w = l1; oh = oh1; ol = ol1; }
    else if (type == 2) { w = l2; oh = ohl2; ol = oll2; }
    else                { w = iw; oh = ohi; ol = oli; }
    w  += (size_t)layer * H_DIM * H_DIM;
    oh += (size_t)layer * H_DIM * HP;
    ol += (size_t)layer * H_DIM * HP;
    const int k0 = blockIdx.x * 64, n0 = blockIdx.y * 64;
    const int tid = threadIdx.x;
    #pragma unroll
    for (int p = 0; p < 4; ++p) {
        int k = p * 16 + (tid >> 4);
        int n4 = (tid & 15) << 2;
        float4 v = make_float4(0.f, 0.f, 0.f, 0.f);
        if (k0 + k < H_DIM && n0 + n4 + 3 < H_DIM)
            v = *(const float4*)(w + (size_t)(k0 + k) * H_DIM + n0 + n4);
        int px = packsplit(v.x), py = packsplit(v.y);
        int pz = packsplit(v.z), pw = packsplit(v.w);
        th[n4 + 0][k] = (short)(px >> 16); tl[n4 + 0][k] = (short)px;
        th[n4 + 1][k] = (short)(py >> 16); tl[n4 + 1][k] = (short)py;
        th[n4 + 2][k] = (short)(pz >> 16); tl[n4 + 2][k] = (short)pz;
        th[n4 + 3][k] = (short)(pw >> 16); tl[n4 + 3][k] = (short)pw;
    }
    __syncthreads();
    #pragma unroll
    for (int p = 0; p < 4; ++p) {
        int n = p * 16 + (tid >> 4);
        int k4 = (tid & 15) << 2;
        if (n0 + n >= H_DIM || k0 + k4 > HP - 4) continue;
        short4 sh = { th[n][k4], th[n][k4 + 1], th[n][k4 + 2], th[n][k4 + 3] };
        short4 sl = { tl[n][k4], tl[n][k4 + 1], tl[n][k4 + 2], tl[n][k4 + 3] };
        *(short4*)(oh + (size_t)(n0 + n) * HP + k0 + k4) = sh;
        *(short4*)(ol + (size_t)(n0 + n) * HP + k0 + k4) = sl;
    }
}

// ---------------------------------------------------------------- helpers
__global__ __launch_bounds__(256)
void init_h_k(const int* __restrict__ z, const float* __restrict__ emb,
              int* __restrict__ hP)
{
    int t = blockIdx.x * 256 + threadIdx.x;
    const int QC = HP / 4;   // 152
    if (t >= N_ATOMS * QC) return;
    int i = t / QC;
    int q = (t - i * QC) << 2;
    size_t idx = (size_t)i * HP + q;
    if (q < H_DIM) {
        float4 v = *(const float4*)(emb + (size_t)z[i] * H_DIM + q);
        *(int4*)(hP + idx) = make_int4(packsplit(v.x), packsplit(v.y),
                                       packsplit(v.z), packsplit(v.w));
    } else {
        *(int4*)(hP + idx) = make_int4(0, 0, 0, 0);
    }
}

// per-edge record: {src*HP, i0*HP, a = C - f*C, b = f*C}
__global__ __launch_bounds__(256)
void edge_geom_k(const float* __restrict__ pos, const int* __restrict__ src,
                 const int* __restrict__ dst, float4* __restrict__ einfo)
{
    int e = blockIdx.x * 256 + threadIdx.x;
    if (e >= E_EDGES) return;
    int s = src[e], d0 = dst[e];
    float dx = pos[s * 3 + 0] - pos[d0 * 3 + 0];
    float dy = pos[s * 3 + 1] - pos[d0 * 3 + 1];
    float dz = pos[s * 3 + 2] - pos[d0 * 3 + 2];
    float dist = sqrtf(dx * dx + dy * dy + dz * dz + 1e-12f);
    float cc = 0.5f * (cosf(dist * 0.31415926535f) + 1.0f);
    float u = dist * ((float)(M_TAB - 1) / DMAX);
    u = fminf(fmaxf(u, 0.0f), (float)(M_TAB - 1) - 0.001f);
    int i0 = (int)u;
    float fc = (u - (float)i0) * cc;
    einfo[e] = make_float4(__int_as_float(s * HP),
                           __int_as_float(i0 * HP),
                           cc - fc, fc);
}

__global__ __launch_bounds__(256)
void rbf_tab_k(int* __restrict__ rtabP)
{
    int t = blockIdx.x * 256 + threadIdx.x;
    if (t >= M_TAB * 64) return;
    int i = t >> 6, g = t & 63;
    float v = 0.0f;
    if (g < G_DIM) {
        float dg  = (float)i * (DMAX / (float)(M_TAB - 1));
        float off = (float)g * (10.0f / 49.0f);
        float x = dg - off;
        const float coeff = -0.5f * (49.0f / 10.0f) * (49.0f / 10.0f);
        v = expf(coeff * x * x);
    }
    rtabP[t] = packsplit(v);
}

// ---------------------------------------------------------------- CSR build
__global__ __launch_bounds__(256)
void hist_k(const int* __restrict__ dst, int* __restrict__ deg)
{
    int e = blockIdx.x * 256 + threadIdx.x;
    if (e >= E_EDGES) return;
    atomicAdd(&deg[dst[e]], 1);
}

__global__ __launch_bounds__(1024)
void scan_k(const int* __restrict__ deg, int* __restrict__ rowptr)
{
    __shared__ int sums[1024];
    int tid = threadIdx.x;
    const int CHUNK = (N_ATOMS + 1023) / 1024;
    int base = tid * CHUNK;
    int local[16];
    int s = 0;
    #pragma unroll
    for (int c = 0; c < 16; ++c) {
        if (c >= CHUNK) break;
        int idx = base + c;
        local[c] = s;
        s += (idx < N_ATOMS) ? deg[idx] : 0;
    }
    sums[tid] = s;
    __syncthreads();
    for (int off = 1; off < 1024; off <<= 1) {
        int v = (tid >= off) ? sums[tid - off] : 0;
        __syncthreads();
        sums[tid] += v;
        __syncthreads();
    }
    int prefix = (tid > 0) ? sums[tid - 1] : 0;
    #pragma unroll
    for (int c = 0; c < 16; ++c) {
        if (c >= CHUNK) break;
        int idx = base + c;
        if (idx <= N_ATOMS) rowptr[idx] = prefix + local[c];
    }
    if (tid == 1023) rowptr[N_ATOMS] = sums[1023];
}

__global__ __launch_bounds__(256)
void fill_k(const int* __restrict__ dst, const float4* __restrict__ einfo,
            const int* __restrict__ rowptr, int* __restrict__ cursor,
            float4* __restrict__ esorted)
{
    int e = blockIdx.x * 256 + threadIdx.x;
    if (e >= E_EDGES) return;
    int d0 = dst[e];
    int pos = rowptr[d0] + atomicAdd(&cursor[d0], 1);
    esorted[pos] = einfo[e];
}

// molecule boundaries via binary search over the SORTED batch array
__global__ __launch_bounds__(256)
void bounds_k(const int* __restrict__ batch, int* __restrict__ mrow)
{
    int b = threadIdx.x;
    if (b > B_MOLS) return;
    int lo = 0, hi = N_ATOMS;
    while (lo < hi) {
        int mid = (lo + hi) >> 1;
        if (batch[mid] < b) lo = mid + 1; else hi = mid;
    }
    mrow[b] = lo;
}

// ---------------------------------------------------------------- gather
__device__ __forceinline__ void gacc(float4& acc, const int* yP, const int* wtP,
                                     const float4& ei, int q)
{
    int srow = __float_as_int(ei.x);
    int wrow = __float_as_int(ei.y);
    float a = ei.z, b = ei.w;
    int4 yv = *(const int4*)(yP + srow + q);
    int4 w0 = *(const int4*)(wtP + wrow + q);
    int4 w1 = *(const int4*)(wtP + wrow + HP + q);
    acc.x += unpackf(yv.x) * (a * unpackf(w0.x) + b * unpackf(w1.x));
    acc.y += unpackf(yv.y) * (a * unpackf(w0.y) + b * unpackf(w1.y));
    acc.z += unpackf(yv.z) * (a * unpackf(w0.z) + b * unpackf(w1.z));
    acc.w += unpackf(yv.w) * (a * unpackf(w0.w) + b * unpackf(w1.w));
}

__global__ __launch_bounds__(256)
void gather_k(const int* __restrict__ yP, const int* __restrict__ wtP,
              const int* __restrict__ rowptr, const float4* __restrict__ esorted,
              int* __restrict__ aggP)
{
    int t = blockIdx.x * 256 + threadIdx.x;
    const int QC = HP / 4;   // 152
    if (t >= N_ATOMS * QC) return;
    int i = t / QC;
    int q = (t - i * QC) << 2;
    size_t idx = (size_t)i * HP + q;
    if (q >= H_DIM) { *(int4*)(aggP + idx) = make_int4(0, 0, 0, 0); return; }
    int j0 = rowptr[i], j1 = rowptr[i + 1];
    float4 a0 = make_float4(0.f, 0.f, 0.f, 0.f);
    float4 a1 = make_float4(0.f, 0.f, 0.f, 0.f);
    int j = j0;
    for (; j + 2 <= j1; j += 2) {
        float4 e0 = esorted[j], e1 = esorted[j + 1];
        gacc(a0, yP, wtP, e0, q);
        gacc(a1, yP, wtP, e1, q);
    }
    if (j < j1) gacc(a0, yP, wtP, esorted[j], q);
    a0.x += a1.x; a0.y += a1.y; a0.z += a1.z; a0.w += a1.w;
    *(int4*)(aggP + idx) = make_int4(packsplit(a0.x), packsplit(a0.y),
                                     packsplit(a0.z), packsplit(a0.w));
}

// ---------------------------------------------------------------- pool (segment mean, no atomics)
__global__ __launch_bounds__(256)
void pool_seg_k(const int* __restrict__ hP, const int* __restrict__ mrow,
                float* __restrict__ pooled)
{
    int b = blockIdx.x;
    int t = threadIdx.x;
    if (t >= 150) return;               // cols 600..607 are pad
    int q = t << 2;
    int a = mrow[b], a1 = mrow[b + 1];
    float cnt = (float)(a1 - a);
    float4 s0 = make_float4(0.f, 0.f, 0.f, 0.f);
    float4 s1 = make_float4(0.f, 0.f, 0.f, 0.f);
    for (; a + 2 <= a1; a += 2) {
        int4 p0 = *(const int4*)(hP + (size_t)a * HP + q);
        int4 p1 = *(const int4*)(hP + (size_t)(a + 1) * HP + q);
        s0.x += unpackf(p0.x); s0.y += unpackf(p0.y);
        s0.z += unpackf(p0.z); s0.w += unpackf(p0.w);
        s1.x += unpackf(p1.x); s1.y += unpackf(p1.y);
        s1.z += unpackf(p1.z); s1.w += unpackf(p1.w);
    }
    if (a < a1) {
        int4 p0 = *(const int4*)(hP + (size_t)a * HP + q);
        s0.x += unpackf(p0.x); s0.y += unpackf(p0.y);
        s0.z += unpackf(p0.z); s0.w += unpackf(p0.w);
    }
    float inv = 1.0f / fmaxf(cnt, 1.0f);
    float4 o = make_float4((s0.x + s1.x) * inv, (s0.y + s1.y) * inv,
                           (s0.z + s1.z) * inv, (s0.w + s1.w) * inv);
    *(float4*)(pooled + (size_t)b * H_DIM + q) = o;
}

// ---------------------------------------------------------------- launch
extern "C" void kernel_launch(void* const* d_in, const int* in_sizes, int n_in,
                              void* d_out, int out_size, void* d_ws, size_t ws_size,
                              hipStream_t stream)
{
    const int*   z      = (const int*)  d_in[0];
    const float* pos    = (const float*)d_in[1];
    const int*   batch  = (const int*)  d_in[2];
    const int*   eidx   = (const int*)  d_in[3];
    const float* emb    = (const float*)d_in[4];
    const float* mlp_w1 = (const float*)d_in[5];
    const float* mlp_b1 = (const float*)d_in[6];
    const float* mlp_w2 = (const float*)d_in[7];
    const float* mlp_b2 = (const float*)d_in[8];
    const float* lin1_w = (const float*)d_in[9];
    const float* lin2_w = (const float*)d_in[10];
    const float* lin2_b = (const float*)d_in[11];
    const float* intw   = (const float*)d_in[12];
    const float* intb   = (const float*)d_in[13];
    const float* poolw  = (const float*)d_in[14];
    const float* poolb  = (const float*)d_in[15];

    float* ws = (float*)d_ws;
    const size_t NHP = (size_t)N_ATOMS * HP;       // 6,080,000
    const size_t TABALL = (size_t)L_LAYERS * M_TAB * HP;   // 3,735,552

    int*   hP    = (int*)ws;                       // NHP
    int*   y1P   = (int*)(ws + NHP);               // NHP; aliases tP, ttabA
    int*   tP    = y1P;
    int*   ttabA = y1P;                            // prep-time alias (3.7M <= NHP)
    int*   aggP  = (int*)(ws + 2 * NHP);           // NHP
    // aggP region aliases — ONLY prep-phase data that's dead before gather:
    float4* einfo  = (float4*)aggP;                          // 256,000 f
    int*    deg    = (int*)((float*)aggP + 300000);          // 10,000
    int*    cursor = (int*)((float*)aggP + 310000);          // 10,000
    int*   wtabA = (int*)(ws + 3 * NHP);           // TABALL (persistent)
    int*   rtabP = (int*)(ws + 3 * NHP + TABALL);  // M_TAB*64 = 65,536
    short* wtH   = (short*)(ws + 3 * NHP + TABALL + (size_t)M_TAB * 64);
    short* wtL   = wtH + 8985600;
    // persistent tail (NOT aliased): esorted, pooled, rowptr, mrow
    float*  tailF   = (float*)(wtL + 8985600);
    float4* esorted = (float4*)tailF;                        // 256,000 f
    float*  pooled  = tailF + 256000;                        // 76,800 f
    int*    rowptr  = (int*)(tailF + 332800);                // 10,001
    int*    mrow    = rowptr + 10001;                        // 129

    short* w1t_h = wtH;                       short* w1t_l = wtL;
    short* w2t_h = wtH + 230400;              short* w2t_l = wtL + 230400;
    short* l1t_h = w2t_h + 6 * 600 * HP;      short* l1t_l = w2t_l + 6 * 600 * HP;
    short* l2t_h = l1t_h + 6 * 600 * HP;      short* l2t_l = l1t_l + 6 * 600 * HP;
    short* int_h = l2t_h + 6 * 600 * HP;      short* int_l = l2t_l + 6 * 600 * HP;

    const int* src = eidx;
    const int* dst = eidx + E_EDGES;

    const dim3 blk(256);
    const int QC = HP / 4;
    const dim3 gN   = mfma_grid(N_ATOMS, H_DIM);            // 1600
    const dim3 gTab = mfma_grid(L_LAYERS * M_TAB, H_DIM);   // 960

    // ---- one-time prep (einfo/deg/cursor alias aggP: dead before gather)
    edge_geom_k<<<(E_EDGES + 255) / 256, blk, 0, stream>>>(pos, src, dst, einfo);
    hipMemsetAsync(deg, 0, 2 * N_ATOMS * sizeof(int), stream);
    hist_k <<<(E_EDGES + 255) / 256, blk, 0, stream>>>(dst, deg);
    scan_k <<<1, 1024, 0, stream>>>(deg, rowptr);
    fill_k <<<(E_EDGES + 255) / 256, blk, 0, stream>>>(dst, einfo, rowptr, cursor, esorted);
    bounds_k <<<1, 256, 0, stream>>>(batch, mrow);
    init_h_k <<<(N_ATOMS * QC + 255) / 256, blk, 0, stream>>>(z, emb, hP);
    rbf_tab_k<<<(M_TAB * 64 + 255) / 256,   blk, 0, stream>>>(rtabP);
    wts_w1_k  <<<dim3(1, 10, 6),   blk, 0, stream>>>(mlp_w1, w1t_h, w1t_l);
    wts_big_k <<<dim3(10, 10, 24), blk, 0, stream>>>(
        mlp_w2, lin1_w, lin2_w, intw,
        w2t_h, w2t_l, l1t_h, l1t_l, l2t_h, l2t_l, int_h, int_l);

    // ---- all 6 layers' filter tables in 2 batched slab GEMMs
    gemm_tab<true, true><<<gTab, blk, 0, stream>>>(
        rtabP, 64, w1t_h, w1t_l, 64, 600 * 64, mlp_b1,
        ttabA, L_LAYERS * M_TAB, 64, H_DIM);
    gemm_tab<false, false><<<gTab, blk, 0, stream>>>(
        ttabA, HP, w2t_h, w2t_l, HP, 600 * HP, mlp_b2,
        wtabA, L_LAYERS * M_TAB, HP, H_DIM);

    for (int k = 0; k < L_LAYERS; ++k) {
        const float* l2b = lin2_b + (size_t)k * H_DIM;
        const float* ib  = intb   + (size_t)k * H_DIM;
        const short* l1h = l1t_h + (size_t)k * H_DIM * HP;
        const short* l1l = l1t_l + (size_t)k * H_DIM * HP;
        const short* l2h = l2t_h + (size_t)k * H_DIM * HP;
        const short* l2l = l2t_l + (size_t)k * H_DIM * HP;
        const short* ih  = int_h + (size_t)k * H_DIM * HP;
        const short* il  = int_l + (size_t)k * H_DIM * HP;
        const int*   wtP = wtabA + (size_t)k * M_TAB * HP;

        // y1P = packsplit(h @ lin1)
        gemm_mfma<false, false, false><<<gN, blk, 0, stream>>>(
            hP, HP, l1h, l1l, HP, nullptr, y1P, N_ATOMS, HP, H_DIM);
        // aggP = packsplit(CSR-gather(y1 * W(d) * C))
        gather_k<<<(N_ATOMS * QC + 255) / 256, blk, 0, stream>>>(
            y1P, wtP, rowptr, esorted, aggP);
        // tP = packsplit(ssp(agg @ lin2 + b))   (aliases y1P)
        gemm_mfma<true, true, false><<<gN, blk, 0, stream>>>(
            aggP, HP, l2h, l2l, HP, l2b, tP, N_ATOMS, HP, H_DIM);
        // hP = packsplit(unpack(hP) + t @ int_w + ib)
        gemm_mfma<true, false, true><<<gN, blk, 0, stream>>>(
            tP, HP, ih, il, HP, ib, hP, N_ATOMS, HP, H_DIM);
    }

    // segment-mean pool (sorted batch, no atomics), then out = pooled @ pool_w + b
    pool_seg_k<<<B_MOLS, blk, 0, stream>>>(hP, mrow, pooled);
    pool_mm2_k<<<dim3(10, B_MOLS), blk, 0, stream>>>(
        pooled, poolw, poolb, (float*)d_out);
}